// Round 2
// baseline (792.917 us; speedup 1.0000x reference)
//
#include <hip/hip_runtime.h>
#include <stdint.h>
#include <math.h>

// MixtureOfDepths: B=4, L=4096, D=1024, Dff=4096, capacity 0.5 -> k=2048.
// This round: inputs/output are FP32 (per reference dtypes + stub rule).
// Compute in bf16 MFMA (no fp32 MFMA on CDNA4), fp32 accumulate, fp32 output.

typedef __attribute__((ext_vector_type(8))) __bf16 bf16x8;
typedef __attribute__((ext_vector_type(4))) __bf16 bf16x4;
typedef __attribute__((ext_vector_type(4))) float f32x4;

__device__ __forceinline__ float gelu_tanh(float x) {
    // jax.nn.gelu default (approximate=True)
    float x3 = x * x * x;
    float t = tanhf(0.7978845608028654f * (x + 0.044715f * x3));
    return 0.5f * x * (1.0f + t);
}

// ---------------- router scores: one wave per token ----------------
__global__ __launch_bounds__(256) void router_scores(
    const float* __restrict__ x, const float* __restrict__ wr,
    float* __restrict__ scores)
{
    int wid  = (blockIdx.x * blockDim.x + threadIdx.x) >> 6;  // token id 0..B*L-1
    int lane = threadIdx.x & 63;
    const float* row = x + (size_t)wid * 1024;
    double s = 0.0;
    #pragma unroll
    for (int it = 0; it < 4; ++it) {
        int base = it * 256 + lane * 4;
        float4 xv = *(const float4*)(row + base);
        float4 wv = *(const float4*)(wr + base);
        s += (double)xv.x * wv.x + (double)xv.y * wv.y
           + (double)xv.z * wv.z + (double)xv.w * wv.w;
    }
    #pragma unroll
    for (int off = 32; off > 0; off >>= 1) s += __shfl_down(s, off, 64);
    if (lane == 0) scores[wid] = (float)s;
}

// ---------------- per-batch top-k + index-list build ----------------
__global__ __launch_bounds__(1024) void topk_build(
    const float* __restrict__ scores,
    int* __restrict__ sel_rows, int* __restrict__ byp_rows)
{
    const int L = 4096, K = 2048;
    __shared__ unsigned long long key[4096];
    __shared__ int flag[4096];
    __shared__ int tsum[1024];
    int b = blockIdx.x, t = threadIdx.x;

    for (int i = t; i < L; i += 1024) {
        unsigned u = __float_as_uint(scores[b * L + i]);
        u = (u & 0x80000000u) ? ~u : (u | 0x80000000u);   // order-preserving map
        key[i] = ((unsigned long long)u << 32) | (unsigned)(L - 1 - i); // tie: low idx wins
    }
    __syncthreads();

    // bitonic sort, descending
    for (int kk = 2; kk <= L; kk <<= 1) {
        for (int j = kk >> 1; j > 0; j >>= 1) {
            for (int i = t; i < L; i += 1024) {
                int p = i ^ j;
                if (p > i) {
                    unsigned long long a = key[i], c = key[p];
                    bool sw = ((i & kk) == 0) ? (a < c) : (a > c);
                    if (sw) { key[i] = c; key[p] = a; }
                }
            }
            __syncthreads();
        }
    }

    // mark selected tokens
    for (int s = t; s < L; s += 1024) {
        int idx = (L - 1) - (int)(key[s] & 0xffffffffu);
        flag[idx] = (s < K) ? 1 : 0;
    }
    __syncthreads();

    // prefix sum: thread owns 4 consecutive tokens
    int base = t * 4;
    int f0 = flag[base], f1 = flag[base+1], f2 = flag[base+2], f3 = flag[base+3];
    tsum[t] = f0 + f1 + f2 + f3;
    __syncthreads();
    for (int off = 1; off < 1024; off <<= 1) {
        int v = tsum[t];
        if (t >= off) v += tsum[t - off];
        __syncthreads();
        tsum[t] = v;
        __syncthreads();
    }
    int run = (t > 0) ? tsum[t - 1] : 0;
    int fl[4] = {f0, f1, f2, f3};
    #pragma unroll
    for (int j = 0; j < 4; ++j) {
        int idx = base + j;
        if (fl[j]) { sel_rows[b * K + run] = b * L + idx; run++; }
        else       { byp_rows[b * (L - K) + (idx - run)] = b * L + idx; }
    }
}

// ---------------- GEMM (BT form): C[m,n] = sum_k A[m,k] * W[n,k] ----------------
// 128x128 tile, BK=64, 256 thr (4 waves, 2x2), 16x16x32 bf16 MFMA, 4x4 frags/wave.
// A dtype templated (fp32 with on-the-fly bf16 cast, or bf16 for the h pass).
// W always fp32 (cast in staging). Padded LDS stride 72 (no swizzle, no async).
template <typename AT, typename OT, bool GATHER_A, bool SCATTER_OUT, bool GELU_ACT>
__global__ __launch_bounds__(256) void gemm_bt(
    const AT* __restrict__ A, const float* __restrict__ W,
    OT* __restrict__ Out, const int* __restrict__ rows,
    int K, int lda, int ldo)
{
    constexpr int BM = 128, BK = 64, LDK = 72;  // 144B rows: 16B-aligned, banks spread
    __shared__ __align__(16) __bf16 As[BM * LDK];
    __shared__ __align__(16) __bf16 Bs[BM * LDK];
    __shared__ int rs[BM];

    const int tid = threadIdx.x;
    const int m0 = blockIdx.y * BM, n0 = blockIdx.x * BM;
    if (tid < BM) rs[tid] = rows ? rows[m0 + tid] : (m0 + tid);
    __syncthreads();

    // ---- staging source row pointers (fixed; only k0 advances) ----
    // fp32 A: 16 rows x 16 float4-cols per pass, 8 passes.
    // bf16 A: 32 rows x 8 bf16x8-cols per pass, 4 passes.
    constexpr bool A_F32 = (sizeof(AT) == 4);
    constexpr int A_PASS = A_F32 ? 8 : 4;
    const int a_rowg = A_F32 ? (tid >> 4) : (tid >> 3);
    const int a_col  = A_F32 ? (tid & 15) : (tid & 7);
    const AT* aptr[A_PASS];
    int a_lrow[A_PASS];
    #pragma unroll
    for (int it = 0; it < A_PASS; ++it) {
        int row = it * (A_F32 ? 16 : 32) + a_rowg;
        int ar = GATHER_A ? rs[row] : (m0 + row);
        aptr[it] = A + (size_t)ar * lda + a_col * (A_F32 ? 4 : 8);
        a_lrow[it] = row;
    }
    const int b_rowg = tid >> 4, b_col = tid & 15;
    const float* bptr[8];
    #pragma unroll
    for (int it = 0; it < 8; ++it)
        bptr[it] = W + (size_t)(n0 + it * 16 + b_rowg) * K + b_col * 4;

    f32x4 acc[4][4] = {};
    const int lane = tid & 63;
    const int wv = tid >> 6;
    const int wr = (wv >> 1) * 64, wc = (wv & 1) * 64;
    const int r = lane & 15, quad = lane >> 4;

    for (int k0 = 0; k0 < K; k0 += BK) {
        // stage A
        #pragma unroll
        for (int it = 0; it < A_PASS; ++it) {
            if (A_F32) {
                float4 v = *(const float4*)((const float*)aptr[it] + k0);
                bf16x4 w;
                w[0] = (__bf16)v.x; w[1] = (__bf16)v.y;
                w[2] = (__bf16)v.z; w[3] = (__bf16)v.w;
                *(bf16x4*)(As + a_lrow[it] * LDK + a_col * 4) = w;
            } else {
                bf16x8 v = *(const bf16x8*)((const __bf16*)aptr[it] + k0);
                *(bf16x8*)(As + a_lrow[it] * LDK + a_col * 8) = v;
            }
        }
        // stage B (always fp32 -> bf16)
        #pragma unroll
        for (int it = 0; it < 8; ++it) {
            float4 v = *(const float4*)(bptr[it] + k0);
            bf16x4 w;
            w[0] = (__bf16)v.x; w[1] = (__bf16)v.y;
            w[2] = (__bf16)v.z; w[3] = (__bf16)v.w;
            *(bf16x4*)(Bs + (it * 16 + b_rowg) * LDK + b_col * 4) = w;
        }
        __syncthreads();

        #pragma unroll
        for (int ks = 0; ks < 2; ++ks) {
            bf16x8 af[4], bfm[4];
            #pragma unroll
            for (int mi = 0; mi < 4; ++mi) {
                int row = wr + mi * 16 + r;
                af[mi] = *(const bf16x8*)(As + row * LDK + (ks * 4 + quad) * 8);
            }
            #pragma unroll
            for (int ni = 0; ni < 4; ++ni) {
                int row = wc + ni * 16 + r;
                bfm[ni] = *(const bf16x8*)(Bs + row * LDK + (ks * 4 + quad) * 8);
            }
            #pragma unroll
            for (int mi = 0; mi < 4; ++mi)
                #pragma unroll
                for (int ni = 0; ni < 4; ++ni)
                    acc[mi][ni] = __builtin_amdgcn_mfma_f32_16x16x32_bf16(
                        af[mi], bfm[ni], acc[mi][ni], 0, 0, 0);
        }
        __syncthreads();
    }

    // epilogue: C/D layout col=lane&15, row=quad*4+reg  [m89-verified]
    #pragma unroll
    for (int mi = 0; mi < 4; ++mi) {
        #pragma unroll
        for (int reg = 0; reg < 4; ++reg) {
            int rowl = wr + mi * 16 + quad * 4 + reg;
            int orow = SCATTER_OUT ? rs[rowl] : (m0 + rowl);
            OT* op = Out + (size_t)orow * ldo + n0;
            #pragma unroll
            for (int ni = 0; ni < 4; ++ni) {
                float v = acc[mi][ni][reg];
                if (GELU_ACT) v = gelu_tanh(v);
                op[wc + ni * 16 + r] = (OT)v;
            }
        }
    }
}

extern "C" void kernel_launch(void* const* d_in, const int* in_sizes, int n_in,
                              void* d_out, int out_size, void* d_ws, size_t ws_size,
                              hipStream_t stream) {
    (void)in_sizes; (void)n_in; (void)out_size; (void)ws_size;
    const float* x  = (const float*)d_in[0];
    const float* wr = (const float*)d_in[1];
    const float* wb = (const float*)d_in[2];
    const float* w1 = (const float*)d_in[3];
    const float* w2 = (const float*)d_in[4];
    float* out = (float*)d_out;

    const int B = 4, L = 4096, D = 1024, DFF = 4096, KSEL = 2048;
    const int M = B * KSEL;  // 8192 selected rows == 8192 bypass rows

    char* ws = (char*)d_ws;
    float* scores = (float*)ws;            ws += sizeof(float) * (size_t)B * L;
    int* sel_rows = (int*)ws;              ws += sizeof(int) * (size_t)M;
    int* byp_rows = (int*)ws;              ws += sizeof(int) * (size_t)M;
    uintptr_t up = ((uintptr_t)ws + 255) & ~(uintptr_t)255;
    __bf16* h = (__bf16*)up;               // per-chunk: 2048 x 4096 bf16 = 16 MiB

    router_scores<<<(B * L) / 4, 256, 0, stream>>>(x, wr, scores);
    topk_build<<<B, 1024, 0, stream>>>(scores, sel_rows, byp_rows);

    // bypass: out[byp_rows] = x[byp_rows] @ wb^T   (M=8192, N=D, K=D)
    gemm_bt<float, float, true, true, false>
        <<<dim3(D / 128, M / 128), 256, 0, stream>>>(
        x, wb, out, byp_rows, D, D, D);

    // FFN, chunked per batch to bound workspace at ~17 MiB
    for (int b = 0; b < B; ++b) {
        const int* selc = sel_rows + b * KSEL;
        // h = gelu(x[selc] @ w1^T)     (M=2048, N=DFF, K=D)
        gemm_bt<float, __bf16, true, false, true>
            <<<dim3(DFF / 128, KSEL / 128), 256, 0, stream>>>(
            x, w1, h, selc, D, D, DFF);
        // out[selc] = h @ w2^T         (M=2048, N=D, K=DFF)
        gemm_bt<__bf16, float, false, true, false>
            <<<dim3(D / 128, KSEL / 128), 256, 0, stream>>>(
            h, w2, out, selc, DFF, DFF, D);
    }
}

// Round 3
// 443.800 us; speedup vs baseline: 1.7867x; 1.7867x over previous
//
#include <hip/hip_runtime.h>
#include <stdint.h>
#include <math.h>

// MixtureOfDepths: B=4, L=4096, D=1024, Dff=4096, capacity 0.5 -> k=2048.
// Inputs/output FP32. Compute in bf16 MFMA (fp32 accumulate).
// R2 -> R3: pre-convert operands to bf16 in ws, un-chunk FFN, m97-style
// async global_load_lds GEMM with XOR-swizzled LDS. Fallback to the
// verified R2 path if ws_size is too small (launch-constant branch).

typedef __attribute__((ext_vector_type(8))) __bf16 bf16x8;
typedef __attribute__((ext_vector_type(4))) __bf16 bf16x4;
typedef __attribute__((ext_vector_type(4))) float f32x4;

__device__ __forceinline__ void async_cp16(const __bf16* g, __bf16* l) {
    __builtin_amdgcn_global_load_lds(
        (__attribute__((address_space(1))) void*)g,
        (__attribute__((address_space(3))) void*)l,
        16, 0, 0);
}

__device__ __forceinline__ float gelu_tanh(float x) {
    float x3 = x * x * x;
    float t = tanhf(0.7978845608028654f * (x + 0.044715f * x3));
    return 0.5f * x * (1.0f + t);
}

// ---------------- fp32 -> bf16 convert (8 elems/thread) ----------------
__global__ __launch_bounds__(256) void cvt_bf16(
    const float* __restrict__ in, __bf16* __restrict__ out, int n)
{
    int i = (blockIdx.x * blockDim.x + threadIdx.x) * 8;
    if (i >= n) return;
    float4 a = *(const float4*)(in + i);
    float4 b = *(const float4*)(in + i + 4);
    bf16x8 v;
    v[0] = (__bf16)a.x; v[1] = (__bf16)a.y; v[2] = (__bf16)a.z; v[3] = (__bf16)a.w;
    v[4] = (__bf16)b.x; v[5] = (__bf16)b.y; v[6] = (__bf16)b.z; v[7] = (__bf16)b.w;
    *(bf16x8*)(out + i) = v;
}

// ---------------- router scores: one wave per token ----------------
__global__ __launch_bounds__(256) void router_scores(
    const float* __restrict__ x, const float* __restrict__ wr,
    float* __restrict__ scores)
{
    int wid  = (blockIdx.x * blockDim.x + threadIdx.x) >> 6;
    int lane = threadIdx.x & 63;
    const float* row = x + (size_t)wid * 1024;
    double s = 0.0;
    #pragma unroll
    for (int it = 0; it < 4; ++it) {
        int base = it * 256 + lane * 4;
        float4 xv = *(const float4*)(row + base);
        float4 wv = *(const float4*)(wr + base);
        s += (double)xv.x * wv.x + (double)xv.y * wv.y
           + (double)xv.z * wv.z + (double)xv.w * wv.w;
    }
    #pragma unroll
    for (int off = 32; off > 0; off >>= 1) s += __shfl_down(s, off, 64);
    if (lane == 0) scores[wid] = (float)s;
}

// ---------------- per-batch top-k + index-list build ----------------
__global__ __launch_bounds__(1024) void topk_build(
    const float* __restrict__ scores,
    int* __restrict__ sel_rows, int* __restrict__ byp_rows)
{
    const int L = 4096, K = 2048;
    __shared__ unsigned long long key[4096];
    __shared__ int flag[4096];
    __shared__ int tsum[1024];
    int b = blockIdx.x, t = threadIdx.x;

    for (int i = t; i < L; i += 1024) {
        unsigned u = __float_as_uint(scores[b * L + i]);
        u = (u & 0x80000000u) ? ~u : (u | 0x80000000u);
        key[i] = ((unsigned long long)u << 32) | (unsigned)(L - 1 - i);
    }
    __syncthreads();

    for (int kk = 2; kk <= L; kk <<= 1) {
        for (int j = kk >> 1; j > 0; j >>= 1) {
            for (int i = t; i < L; i += 1024) {
                int p = i ^ j;
                if (p > i) {
                    unsigned long long a = key[i], c = key[p];
                    bool sw = ((i & kk) == 0) ? (a < c) : (a > c);
                    if (sw) { key[i] = c; key[p] = a; }
                }
            }
            __syncthreads();
        }
    }

    for (int s = t; s < L; s += 1024) {
        int idx = (L - 1) - (int)(key[s] & 0xffffffffu);
        flag[idx] = (s < K) ? 1 : 0;
    }
    __syncthreads();

    int base = t * 4;
    int f0 = flag[base], f1 = flag[base+1], f2 = flag[base+2], f3 = flag[base+3];
    tsum[t] = f0 + f1 + f2 + f3;
    __syncthreads();
    for (int off = 1; off < 1024; off <<= 1) {
        int v = tsum[t];
        if (t >= off) v += tsum[t - off];
        __syncthreads();
        tsum[t] = v;
        __syncthreads();
    }
    int run = (t > 0) ? tsum[t - 1] : 0;
    int fl[4] = {f0, f1, f2, f3};
    #pragma unroll
    for (int j = 0; j < 4; ++j) {
        int idx = base + j;
        if (fl[j]) { sel_rows[b * K + run] = b * L + idx; run++; }
        else       { byp_rows[b * (L - K) + (idx - run)] = b * L + idx; }
    }
}

// ======== PATH A: m97-style async GEMM, all-bf16 operands ========
// C[m,n] = sum_k A[m,k] * W[n,k]; 128x128 tile, BK=64, 4 waves (2x2), 4x4 frags.
// global_load_lds width 16; XOR-swizzled LDS: slot s of row r holds chunk s^(r&7).
template <bool GATHER_A, bool SCATTER_OUT, bool GELU_ACT, typename OT>
__global__ __launch_bounds__(256) void gemm_async(
    const __bf16* __restrict__ A, const __bf16* __restrict__ W,
    OT* __restrict__ Out, const int* __restrict__ rows,
    int K, int lda, int ldo)
{
    constexpr int BM = 128, BK = 64;
    __shared__ __align__(16) __bf16 As[BM * BK];
    __shared__ __align__(16) __bf16 Bs[BM * BK];
    __shared__ int rs[BM];

    const int tid = threadIdx.x;
    const int m0 = blockIdx.y * BM, n0 = blockIdx.x * BM;
    if (tid < BM) rs[tid] = rows ? rows[m0 + tid] : (m0 + tid);
    __syncthreads();

    const int sub = tid >> 3;                // row within 32-row stripe (0..31)
    const int gc  = (tid & 7) ^ (sub & 7);   // swizzled source chunk
    const __bf16* aptr[4]; const __bf16* bptr[4];
    __bf16* adst[4]; __bf16* bdst[4];
    #pragma unroll
    for (int i = 0; i < 4; ++i) {
        int row = i * 32 + sub;
        int ar  = GATHER_A ? rs[row] : (m0 + row);
        aptr[i] = A + (size_t)ar * lda + gc * 8;
        bptr[i] = W + (size_t)(n0 + row) * K + gc * 8;
        adst[i] = As + (i * 256 + tid) * 8;  // = base + lane*16B within each wave
        bdst[i] = Bs + (i * 256 + tid) * 8;
    }

    f32x4 acc[4][4] = {};
    const int lane = tid & 63;
    const int wv = tid >> 6;
    const int wr = (wv >> 1) * 64, wc = (wv & 1) * 64;
    const int r = lane & 15, quad = lane >> 4;

    for (int k0 = 0; k0 < K; k0 += BK) {
        #pragma unroll
        for (int i = 0; i < 4; ++i) async_cp16(aptr[i] + k0, adst[i]);
        #pragma unroll
        for (int i = 0; i < 4; ++i) async_cp16(bptr[i] + k0, bdst[i]);
        __syncthreads();

        #pragma unroll
        for (int ks = 0; ks < 2; ++ks) {
            bf16x8 af[4], bfm[4];
            #pragma unroll
            for (int mi = 0; mi < 4; ++mi) {
                int row = wr + mi * 16 + r;
                int swz = (ks * 4 + quad) ^ (row & 7);
                af[mi] = *(const bf16x8*)(As + row * BK + swz * 8);
            }
            #pragma unroll
            for (int ni = 0; ni < 4; ++ni) {
                int row = wc + ni * 16 + r;
                int swz = (ks * 4 + quad) ^ (row & 7);
                bfm[ni] = *(const bf16x8*)(Bs + row * BK + swz * 8);
            }
            #pragma unroll
            for (int mi = 0; mi < 4; ++mi)
                #pragma unroll
                for (int ni = 0; ni < 4; ++ni)
                    acc[mi][ni] = __builtin_amdgcn_mfma_f32_16x16x32_bf16(
                        af[mi], bfm[ni], acc[mi][ni], 0, 0, 0);
        }
        __syncthreads();
    }

    // epilogue: C/D layout col=lane&15, row=quad*4+reg  [R2-verified]
    #pragma unroll
    for (int mi = 0; mi < 4; ++mi) {
        #pragma unroll
        for (int reg = 0; reg < 4; ++reg) {
            int rowl = wr + mi * 16 + quad * 4 + reg;
            int orow = SCATTER_OUT ? rs[rowl] : (m0 + rowl);
            OT* op = Out + (size_t)orow * ldo + n0;
            #pragma unroll
            for (int ni = 0; ni < 4; ++ni) {
                float v = acc[mi][ni][reg];
                if (GELU_ACT) v = gelu_tanh(v);
                op[wc + ni * 16 + r] = (OT)v;
            }
        }
    }
}

// ======== PATH B (fallback, R2-verified): register-staging GEMM ========
template <typename AT, typename OT, bool GATHER_A, bool SCATTER_OUT, bool GELU_ACT>
__global__ __launch_bounds__(256) void gemm_bt(
    const AT* __restrict__ A, const float* __restrict__ W,
    OT* __restrict__ Out, const int* __restrict__ rows,
    int K, int lda, int ldo)
{
    constexpr int BM = 128, BK = 64, LDK = 72;
    __shared__ __align__(16) __bf16 As[BM * LDK];
    __shared__ __align__(16) __bf16 Bs[BM * LDK];
    __shared__ int rs[BM];

    const int tid = threadIdx.x;
    const int m0 = blockIdx.y * BM, n0 = blockIdx.x * BM;
    if (tid < BM) rs[tid] = rows ? rows[m0 + tid] : (m0 + tid);
    __syncthreads();

    constexpr bool A_F32 = (sizeof(AT) == 4);
    constexpr int A_PASS = A_F32 ? 8 : 4;
    const int a_rowg = A_F32 ? (tid >> 4) : (tid >> 3);
    const int a_col  = A_F32 ? (tid & 15) : (tid & 7);
    const AT* aptr[A_PASS];
    int a_lrow[A_PASS];
    #pragma unroll
    for (int it = 0; it < A_PASS; ++it) {
        int row = it * (A_F32 ? 16 : 32) + a_rowg;
        int ar = GATHER_A ? rs[row] : (m0 + row);
        aptr[it] = A + (size_t)ar * lda + a_col * (A_F32 ? 4 : 8);
        a_lrow[it] = row;
    }
    const int b_rowg = tid >> 4, b_col = tid & 15;
    const float* bptr[8];
    #pragma unroll
    for (int it = 0; it < 8; ++it)
        bptr[it] = W + (size_t)(n0 + it * 16 + b_rowg) * K + b_col * 4;

    f32x4 acc[4][4] = {};
    const int lane = tid & 63;
    const int wv = tid >> 6;
    const int wr = (wv >> 1) * 64, wc = (wv & 1) * 64;
    const int r = lane & 15, quad = lane >> 4;

    for (int k0 = 0; k0 < K; k0 += BK) {
        #pragma unroll
        for (int it = 0; it < A_PASS; ++it) {
            if (A_F32) {
                float4 v = *(const float4*)((const float*)aptr[it] + k0);
                bf16x4 w;
                w[0] = (__bf16)v.x; w[1] = (__bf16)v.y;
                w[2] = (__bf16)v.z; w[3] = (__bf16)v.w;
                *(bf16x4*)(As + a_lrow[it] * LDK + a_col * 4) = w;
            } else {
                bf16x8 v = *(const bf16x8*)((const __bf16*)aptr[it] + k0);
                *(bf16x8*)(As + a_lrow[it] * LDK + a_col * 8) = v;
            }
        }
        #pragma unroll
        for (int it = 0; it < 8; ++it) {
            float4 v = *(const float4*)(bptr[it] + k0);
            bf16x4 w;
            w[0] = (__bf16)v.x; w[1] = (__bf16)v.y;
            w[2] = (__bf16)v.z; w[3] = (__bf16)v.w;
            *(bf16x4*)(Bs + (it * 16 + b_rowg) * LDK + b_col * 4) = w;
        }
        __syncthreads();

        #pragma unroll
        for (int ks = 0; ks < 2; ++ks) {
            bf16x8 af[4], bfm[4];
            #pragma unroll
            for (int mi = 0; mi < 4; ++mi) {
                int row = wr + mi * 16 + r;
                af[mi] = *(const bf16x8*)(As + row * LDK + (ks * 4 + quad) * 8);
            }
            #pragma unroll
            for (int ni = 0; ni < 4; ++ni) {
                int row = wc + ni * 16 + r;
                bfm[ni] = *(const bf16x8*)(Bs + row * LDK + (ks * 4 + quad) * 8);
            }
            #pragma unroll
            for (int mi = 0; mi < 4; ++mi)
                #pragma unroll
                for (int ni = 0; ni < 4; ++ni)
                    acc[mi][ni] = __builtin_amdgcn_mfma_f32_16x16x32_bf16(
                        af[mi], bfm[ni], acc[mi][ni], 0, 0, 0);
        }
        __syncthreads();
    }

    #pragma unroll
    for (int mi = 0; mi < 4; ++mi) {
        #pragma unroll
        for (int reg = 0; reg < 4; ++reg) {
            int rowl = wr + mi * 16 + quad * 4 + reg;
            int orow = SCATTER_OUT ? rs[rowl] : (m0 + rowl);
            OT* op = Out + (size_t)orow * ldo + n0;
            #pragma unroll
            for (int ni = 0; ni < 4; ++ni) {
                float v = acc[mi][ni][reg];
                if (GELU_ACT) v = gelu_tanh(v);
                op[wc + ni * 16 + r] = (OT)v;
            }
        }
    }
}

extern "C" void kernel_launch(void* const* d_in, const int* in_sizes, int n_in,
                              void* d_out, int out_size, void* d_ws, size_t ws_size,
                              hipStream_t stream) {
    (void)in_sizes; (void)n_in; (void)out_size;
    const float* x  = (const float*)d_in[0];
    const float* wr = (const float*)d_in[1];
    const float* wb = (const float*)d_in[2];
    const float* w1 = (const float*)d_in[3];
    const float* w2 = (const float*)d_in[4];
    float* out = (float*)d_out;

    const int B = 4, L = 4096, D = 1024, DFF = 4096, KSEL = 2048;
    const int M = B * KSEL;           // 8192 selected rows == 8192 bypass rows
    const int NTOK = B * L;           // 16384

    // ---- workspace layout ----
    char* ws = (char*)d_ws;
    float* scores = (float*)ws;            ws += sizeof(float) * (size_t)NTOK;
    int* sel_rows = (int*)ws;              ws += sizeof(int) * (size_t)M;
    int* byp_rows = (int*)ws;              ws += sizeof(int) * (size_t)M;
    uintptr_t up = ((uintptr_t)ws + 255) & ~(uintptr_t)255;

    // Path-A extras
    size_t n_x = (size_t)NTOK * D, n_wb = (size_t)D * D;
    size_t n_w1 = (size_t)DFF * D, n_w2 = (size_t)D * DFF;
    size_t n_h = (size_t)M * DFF;
    size_t needA = (up - (uintptr_t)d_ws)
                 + 2 * (n_x + n_wb + n_w1 + n_w2 + n_h) + 1024;

    router_scores<<<NTOK / 4, 256, 0, stream>>>(x, wr, scores);
    topk_build<<<B, 1024, 0, stream>>>(scores, sel_rows, byp_rows);

    if (ws_size >= needA) {
        __bf16* xb  = (__bf16*)up;        up += 2 * n_x;
        __bf16* wbb = (__bf16*)up;        up += 2 * n_wb;
        __bf16* w1b = (__bf16*)up;        up += 2 * n_w1;
        __bf16* w2b = (__bf16*)up;        up += 2 * n_w2;
        up = (up + 255) & ~(uintptr_t)255;
        __bf16* h   = (__bf16*)up;        // 8192 x 4096 bf16 = 64 MiB

        cvt_bf16<<<(int)(n_x  / 8 + 255) / 256 * 1 + ((n_x % 2048)?1:0), 256, 0, stream>>>(x,  xb,  (int)n_x);
        cvt_bf16<<<(int)((n_wb / 8 + 255) / 256), 256, 0, stream>>>(wb, wbb, (int)n_wb);
        cvt_bf16<<<(int)((n_w1 / 8 + 255) / 256), 256, 0, stream>>>(w1, w1b, (int)n_w1);
        cvt_bf16<<<(int)((n_w2 / 8 + 255) / 256), 256, 0, stream>>>(w2, w2b, (int)n_w2);

        // bypass: out[byp] = x[byp] @ wb^T      (M=8192, N=D, K=D)
        gemm_async<true, true, false, float>
            <<<dim3(D / 128, M / 128), 256, 0, stream>>>(
            xb, wbb, out, byp_rows, D, D, D);
        // h = gelu(x[sel] @ w1^T)               (M=8192, N=DFF, K=D)
        gemm_async<true, false, true, __bf16>
            <<<dim3(DFF / 128, M / 128), 256, 0, stream>>>(
            xb, w1b, h, sel_rows, D, D, DFF);
        // out[sel] = h @ w2^T                   (M=8192, N=D, K=DFF)
        gemm_async<false, true, false, float>
            <<<dim3(D / 128, M / 128), 256, 0, stream>>>(
            h, w2b, out, sel_rows, DFF, DFF, D);
    } else {
        // R2-verified fallback (chunked, fp32 register staging)
        __bf16* h = (__bf16*)up;          // per-chunk: 2048 x 4096 bf16 = 16 MiB
        gemm_bt<float, float, true, true, false>
            <<<dim3(D / 128, M / 128), 256, 0, stream>>>(
            x, wb, out, byp_rows, D, D, D);
        for (int b = 0; b < B; ++b) {
            const int* selc = sel_rows + b * KSEL;
            gemm_bt<float, __bf16, true, false, true>
                <<<dim3(DFF / 128, KSEL / 128), 256, 0, stream>>>(
                x, w1, h, selc, D, D, DFF);
            gemm_bt<__bf16, float, false, true, false>
                <<<dim3(D / 128, KSEL / 128), 256, 0, stream>>>(
                h, w2, out, selc, DFF, DFF, D);
        }
    }
}

// Round 4
// 421.640 us; speedup vs baseline: 1.8806x; 1.0526x over previous
//
#include <hip/hip_runtime.h>
#include <stdint.h>
#include <math.h>

// MixtureOfDepths: B=4, L=4096, D=1024, Dff=4096, capacity 0.5 -> k=2048.
// Inputs/output FP32; compute bf16 MFMA (fp32 accumulate).
// R3 -> R4: fast sigmoid-GELU (epilogue was VALU-bound: 64 tanhf = ~3200cyc
// vs 1240cyc of MFMA), x-cvt fused into router pass, bypass merged into the
// FFN2 dispatch (1024 blocks = 4/CU instead of two serial 512-block launches).

typedef __attribute__((ext_vector_type(8))) __bf16 bf16x8;
typedef __attribute__((ext_vector_type(4))) float f32x4;

__device__ __forceinline__ void async_cp16(const __bf16* g, __bf16* l) {
    __builtin_amdgcn_global_load_lds(
        (__attribute__((address_space(1))) void*)g,
        (__attribute__((address_space(3))) void*)l,
        16, 0, 0);
}

// gelu_tanh(x) == x * sigmoid(2*0.7978845608*(x + 0.044715 x^3)), exactly.
__device__ __forceinline__ float gelu_fast(float x) {
    float u = 1.5957691216057308f * x * (1.0f + 0.044715f * x * x);
    return x / (1.0f + __expf(-u));
}

// ---------- router scores + fused x -> bf16 convert (one wave/token) ----------
__global__ __launch_bounds__(256) void router_cvt(
    const float* __restrict__ x, const float* __restrict__ wr,
    float* __restrict__ scores, __bf16* __restrict__ xb)
{
    int wid  = (blockIdx.x * blockDim.x + threadIdx.x) >> 6;  // token id
    int lane = threadIdx.x & 63;
    const float* row = x + (size_t)wid * 1024;
    __bf16* orow = xb + (size_t)wid * 1024;
    double s = 0.0;
    #pragma unroll
    for (int it = 0; it < 2; ++it) {
        int base = it * 512 + lane * 8;
        float4 a  = *(const float4*)(row + base);
        float4 b  = *(const float4*)(row + base + 4);
        float4 wa = *(const float4*)(wr + base);
        float4 wc = *(const float4*)(wr + base + 4);
        s += (double)a.x * wa.x + (double)a.y * wa.y
           + (double)a.z * wa.z + (double)a.w * wa.w
           + (double)b.x * wc.x + (double)b.y * wc.y
           + (double)b.z * wc.z + (double)b.w * wc.w;
        bf16x8 v;
        v[0] = (__bf16)a.x; v[1] = (__bf16)a.y; v[2] = (__bf16)a.z; v[3] = (__bf16)a.w;
        v[4] = (__bf16)b.x; v[5] = (__bf16)b.y; v[6] = (__bf16)b.z; v[7] = (__bf16)b.w;
        *(bf16x8*)(orow + base) = v;
    }
    #pragma unroll
    for (int off = 32; off > 0; off >>= 1) s += __shfl_down(s, off, 64);
    if (lane == 0) scores[wid] = (float)s;
}

// ---------- weights -> bf16, three segments in one launch ----------
__global__ __launch_bounds__(256) void cvt3(
    const float* __restrict__ p0, const float* __restrict__ p1,
    const float* __restrict__ p2,
    __bf16* __restrict__ o0, __bf16* __restrict__ o1, __bf16* __restrict__ o2,
    int c0, int c1, int c2)  // 8-elem chunk counts per segment
{
    int chunk = blockIdx.x * 256 + threadIdx.x;
    const float* in; __bf16* out;
    if (chunk < c0)                { in = p0 + (size_t)chunk * 8;             out = o0 + (size_t)chunk * 8; }
    else if (chunk < c0 + c1)      { int c = chunk - c0;      in = p1 + (size_t)c * 8; out = o1 + (size_t)c * 8; }
    else if (chunk < c0 + c1 + c2) { int c = chunk - c0 - c1; in = p2 + (size_t)c * 8; out = o2 + (size_t)c * 8; }
    else return;
    float4 a = *(const float4*)(in);
    float4 b = *(const float4*)(in + 4);
    bf16x8 v;
    v[0] = (__bf16)a.x; v[1] = (__bf16)a.y; v[2] = (__bf16)a.z; v[3] = (__bf16)a.w;
    v[4] = (__bf16)b.x; v[5] = (__bf16)b.y; v[6] = (__bf16)b.z; v[7] = (__bf16)b.w;
    *(bf16x8*)(out) = v;
}

// ---------------- per-batch top-k + index-list build ----------------
__global__ __launch_bounds__(1024) void topk_build(
    const float* __restrict__ scores,
    int* __restrict__ sel_rows, int* __restrict__ byp_rows)
{
    const int L = 4096, K = 2048;
    __shared__ unsigned long long key[4096];
    __shared__ int flag[4096];
    __shared__ int tsum[1024];
    int b = blockIdx.x, t = threadIdx.x;

    for (int i = t; i < L; i += 1024) {
        unsigned u = __float_as_uint(scores[b * L + i]);
        u = (u & 0x80000000u) ? ~u : (u | 0x80000000u);
        key[i] = ((unsigned long long)u << 32) | (unsigned)(L - 1 - i);
    }
    __syncthreads();

    for (int kk = 2; kk <= L; kk <<= 1) {
        for (int j = kk >> 1; j > 0; j >>= 1) {
            for (int i = t; i < L; i += 1024) {
                int p = i ^ j;
                if (p > i) {
                    unsigned long long a = key[i], c = key[p];
                    bool sw = ((i & kk) == 0) ? (a < c) : (a > c);
                    if (sw) { key[i] = c; key[p] = a; }
                }
            }
            __syncthreads();
        }
    }

    for (int s = t; s < L; s += 1024) {
        int idx = (L - 1) - (int)(key[s] & 0xffffffffu);
        flag[idx] = (s < K) ? 1 : 0;
    }
    __syncthreads();

    int base = t * 4;
    int f0 = flag[base], f1 = flag[base+1], f2 = flag[base+2], f3 = flag[base+3];
    tsum[t] = f0 + f1 + f2 + f3;
    __syncthreads();
    for (int off = 1; off < 1024; off <<= 1) {
        int v = tsum[t];
        if (t >= off) v += tsum[t - off];
        __syncthreads();
        tsum[t] = v;
        __syncthreads();
    }
    int run = (t > 0) ? tsum[t - 1] : 0;
    int fl[4] = {f0, f1, f2, f3};
    #pragma unroll
    for (int j = 0; j < 4; ++j) {
        int idx = base + j;
        if (fl[j]) { sel_rows[b * K + run] = b * L + idx; run++; }
        else       { byp_rows[b * (L - K) + (idx - run)] = b * L + idx; }
    }
}

// ======== m97-style async GEMM, all-bf16 operands ========
// C[m,n] = sum_k A[m,k] * W[n,k]; 128x128 tile, BK=64, 4 waves (2x2), 4x4 frags.
// global_load_lds width 16; XOR-swizzled LDS: slot s of row r holds chunk s^(r&7).
template <bool GATHER_A, bool SCATTER_OUT, bool GELU_ACT, typename OT>
__global__ __launch_bounds__(256) void gemm_async(
    const __bf16* __restrict__ A, const __bf16* __restrict__ W,
    OT* __restrict__ Out, const int* __restrict__ rows,
    int K, int lda, int ldo)
{
    constexpr int BM = 128, BK = 64;
    __shared__ __align__(16) __bf16 As[BM * BK];
    __shared__ __align__(16) __bf16 Bs[BM * BK];
    __shared__ int rs[BM];

    const int tid = threadIdx.x;
    const int m0 = blockIdx.y * BM, n0 = blockIdx.x * BM;
    if (tid < BM) rs[tid] = rows ? rows[m0 + tid] : (m0 + tid);
    __syncthreads();

    const int sub = tid >> 3;
    const int gc  = (tid & 7) ^ (sub & 7);
    const __bf16* aptr[4]; const __bf16* bptr[4];
    __bf16* adst[4]; __bf16* bdst[4];
    #pragma unroll
    for (int i = 0; i < 4; ++i) {
        int row = i * 32 + sub;
        int ar  = GATHER_A ? rs[row] : (m0 + row);
        aptr[i] = A + (size_t)ar * lda + gc * 8;
        bptr[i] = W + (size_t)(n0 + row) * K + gc * 8;
        adst[i] = As + (i * 256 + tid) * 8;
        bdst[i] = Bs + (i * 256 + tid) * 8;
    }

    f32x4 acc[4][4] = {};
    const int lane = tid & 63;
    const int wv = tid >> 6;
    const int wr = (wv >> 1) * 64, wc = (wv & 1) * 64;
    const int r = lane & 15, quad = lane >> 4;

    for (int k0 = 0; k0 < K; k0 += BK) {
        #pragma unroll
        for (int i = 0; i < 4; ++i) async_cp16(aptr[i] + k0, adst[i]);
        #pragma unroll
        for (int i = 0; i < 4; ++i) async_cp16(bptr[i] + k0, bdst[i]);
        __syncthreads();

        #pragma unroll
        for (int ks = 0; ks < 2; ++ks) {
            bf16x8 af[4], bfm[4];
            #pragma unroll
            for (int mi = 0; mi < 4; ++mi) {
                int row = wr + mi * 16 + r;
                int swz = (ks * 4 + quad) ^ (row & 7);
                af[mi] = *(const bf16x8*)(As + row * BK + swz * 8);
            }
            #pragma unroll
            for (int ni = 0; ni < 4; ++ni) {
                int row = wc + ni * 16 + r;
                int swz = (ks * 4 + quad) ^ (row & 7);
                bfm[ni] = *(const bf16x8*)(Bs + row * BK + swz * 8);
            }
            #pragma unroll
            for (int mi = 0; mi < 4; ++mi)
                #pragma unroll
                for (int ni = 0; ni < 4; ++ni)
                    acc[mi][ni] = __builtin_amdgcn_mfma_f32_16x16x32_bf16(
                        af[mi], bfm[ni], acc[mi][ni], 0, 0, 0);
        }
        __syncthreads();
    }

    // epilogue: C/D layout col=lane&15, row=quad*4+reg  [R2/R3-verified]
    #pragma unroll
    for (int mi = 0; mi < 4; ++mi) {
        #pragma unroll
        for (int reg = 0; reg < 4; ++reg) {
            int rowl = wr + mi * 16 + quad * 4 + reg;
            int orow = SCATTER_OUT ? rs[rowl] : (m0 + rowl);
            OT* op = Out + (size_t)orow * ldo + n0;
            #pragma unroll
            for (int ni = 0; ni < 4; ++ni) {
                float v = acc[mi][ni][reg];
                if (GELU_ACT) v = gelu_fast(v);
                op[wc + ni * 16 + r] = (OT)v;
            }
        }
    }
}

// ======== merged tail: blockIdx.z==0 -> FFN2 (h@w2^T, scatter sel),
//                       blockIdx.z==1 -> bypass (x@wb^T, gather+scatter byp) ====
__global__ __launch_bounds__(256) void gemm_tail(
    const __bf16* __restrict__ h, const __bf16* __restrict__ w2b,
    const __bf16* __restrict__ xb, const __bf16* __restrict__ wbb,
    float* __restrict__ Out,
    const int* __restrict__ sel_rows, const int* __restrict__ byp_rows)
{
    constexpr int BM = 128, BK = 64;
    __shared__ __align__(16) __bf16 As[BM * BK];
    __shared__ __align__(16) __bf16 Bs[BM * BK];
    __shared__ int rs[BM];

    const int z = blockIdx.z;                 // 0: FFN2, 1: bypass
    const __bf16* A = z ? xb : h;
    const __bf16* W = z ? wbb : w2b;
    const int K = z ? 1024 : 4096;            // == lda for both
    const int* rows = z ? byp_rows : sel_rows;
    const bool gat = (z != 0);

    const int tid = threadIdx.x;
    const int m0 = blockIdx.y * BM, n0 = blockIdx.x * BM;
    rs[tid & 127] = rows[m0 + (tid & 127)];
    __syncthreads();

    const int sub = tid >> 3;
    const int gc  = (tid & 7) ^ (sub & 7);
    const __bf16* aptr[4]; const __bf16* bptr[4];
    __bf16* adst[4]; __bf16* bdst[4];
    #pragma unroll
    for (int i = 0; i < 4; ++i) {
        int row = i * 32 + sub;
        int ar  = gat ? rs[row] : (m0 + row);
        aptr[i] = A + (size_t)ar * K + gc * 8;
        bptr[i] = W + (size_t)(n0 + row) * K + gc * 8;
        adst[i] = As + (i * 256 + tid) * 8;
        bdst[i] = Bs + (i * 256 + tid) * 8;
    }

    f32x4 acc[4][4] = {};
    const int lane = tid & 63;
    const int wv = tid >> 6;
    const int wrr = (wv >> 1) * 64, wc = (wv & 1) * 64;
    const int r = lane & 15, quad = lane >> 4;

    for (int k0 = 0; k0 < K; k0 += BK) {
        #pragma unroll
        for (int i = 0; i < 4; ++i) async_cp16(aptr[i] + k0, adst[i]);
        #pragma unroll
        for (int i = 0; i < 4; ++i) async_cp16(bptr[i] + k0, bdst[i]);
        __syncthreads();

        #pragma unroll
        for (int ks = 0; ks < 2; ++ks) {
            bf16x8 af[4], bfm[4];
            #pragma unroll
            for (int mi = 0; mi < 4; ++mi) {
                int row = wrr + mi * 16 + r;
                int swz = (ks * 4 + quad) ^ (row & 7);
                af[mi] = *(const bf16x8*)(As + row * BK + swz * 8);
            }
            #pragma unroll
            for (int ni = 0; ni < 4; ++ni) {
                int row = wc + ni * 16 + r;
                int swz = (ks * 4 + quad) ^ (row & 7);
                bfm[ni] = *(const bf16x8*)(Bs + row * BK + swz * 8);
            }
            #pragma unroll
            for (int mi = 0; mi < 4; ++mi)
                #pragma unroll
                for (int ni = 0; ni < 4; ++ni)
                    acc[mi][ni] = __builtin_amdgcn_mfma_f32_16x16x32_bf16(
                        af[mi], bfm[ni], acc[mi][ni], 0, 0, 0);
        }
        __syncthreads();
    }

    #pragma unroll
    for (int mi = 0; mi < 4; ++mi) {
        #pragma unroll
        for (int reg = 0; reg < 4; ++reg) {
            int rowl = wrr + mi * 16 + quad * 4 + reg;
            int orow = rs[rowl];
            float* op = Out + (size_t)orow * 1024 + n0;
            #pragma unroll
            for (int ni = 0; ni < 4; ++ni)
                op[wc + ni * 16 + r] = acc[mi][ni][reg];
        }
    }
}

extern "C" void kernel_launch(void* const* d_in, const int* in_sizes, int n_in,
                              void* d_out, int out_size, void* d_ws, size_t ws_size,
                              hipStream_t stream) {
    (void)in_sizes; (void)n_in; (void)out_size; (void)ws_size;
    const float* x  = (const float*)d_in[0];
    const float* wr = (const float*)d_in[1];
    const float* wb = (const float*)d_in[2];
    const float* w1 = (const float*)d_in[3];
    const float* w2 = (const float*)d_in[4];
    float* out = (float*)d_out;

    const int B = 4, L = 4096, D = 1024, DFF = 4096, KSEL = 2048;
    const int M = B * KSEL;           // 8192
    const int NTOK = B * L;           // 16384

    size_t n_x = (size_t)NTOK * D, n_wb = (size_t)D * D;
    size_t n_w1 = (size_t)DFF * D, n_w2 = (size_t)D * DFF;

    char* ws = (char*)d_ws;
    float* scores = (float*)ws;            ws += sizeof(float) * (size_t)NTOK;
    int* sel_rows = (int*)ws;              ws += sizeof(int) * (size_t)M;
    int* byp_rows = (int*)ws;              ws += sizeof(int) * (size_t)M;
    uintptr_t up = ((uintptr_t)ws + 255) & ~(uintptr_t)255;
    __bf16* xb  = (__bf16*)up;             up += 2 * n_x;
    __bf16* wbb = (__bf16*)up;             up += 2 * n_wb;
    __bf16* w1b = (__bf16*)up;             up += 2 * n_w1;
    __bf16* w2b = (__bf16*)up;             up += 2 * n_w2;
    up = (up + 255) & ~(uintptr_t)255;
    __bf16* h   = (__bf16*)up;             // 8192 x 4096 bf16 = 64 MiB

    router_cvt<<<NTOK / 4, 256, 0, stream>>>(x, wr, scores, xb);
    cvt3<<<(int)((n_wb + n_w1 + n_w2) / 8 / 256), 256, 0, stream>>>(
        wb, w1, w2, wbb, w1b, w2b,
        (int)(n_wb / 8), (int)(n_w1 / 8), (int)(n_w2 / 8));
    topk_build<<<B, 1024, 0, stream>>>(scores, sel_rows, byp_rows);

    // h = gelu(x[sel] @ w1^T)     (M=8192, N=DFF, K=D), 2048 blocks
    gemm_async<true, false, true, __bf16>
        <<<dim3(DFF / 128, M / 128), 256, 0, stream>>>(
        xb, w1b, h, sel_rows, D, D, DFF);
    // merged: out[sel] = h @ w2^T  and  out[byp] = x[byp] @ wb^T, 1024 blocks
    gemm_tail<<<dim3(D / 128, M / 128, 2), 256, 0, stream>>>(
        h, w2b, xb, wbb, out, sel_rows, byp_rows);
}

// Round 5
// 377.834 us; speedup vs baseline: 2.0986x; 1.1159x over previous
//
#include <hip/hip_runtime.h>
#include <stdint.h>
#include <math.h>

// MixtureOfDepths: B=4, L=4096, D=1024, Dff=4096, capacity 0.5 -> k=2048.
// Inputs/output FP32; compute bf16 MFMA (fp32 accumulate).
// R4 -> R5: bitonic topk (4 CUs, ~100us) -> radix-select (<10us);
// XCD-aware block swizzle in GEMMs (A-tile reuse within one XCD's L2;
// tail FETCH was 333MB vs ~90MB ideal).

typedef __attribute__((ext_vector_type(8))) __bf16 bf16x8;
typedef __attribute__((ext_vector_type(4))) float f32x4;

__device__ __forceinline__ void async_cp16(const __bf16* g, __bf16* l) {
    __builtin_amdgcn_global_load_lds(
        (__attribute__((address_space(1))) void*)g,
        (__attribute__((address_space(3))) void*)l,
        16, 0, 0);
}

// gelu_tanh(x) == x * sigmoid(2*0.7978845608*(x + 0.044715 x^3)), exactly.
__device__ __forceinline__ float gelu_fast(float x) {
    float u = 1.5957691216057308f * x * (1.0f + 0.044715f * x * x);
    return x / (1.0f + __expf(-u));
}

// ---------- router scores + fused x -> bf16 convert (one wave/token) ----------
// NOTE: score math must stay bit-identical across rounds (selection boundary).
__global__ __launch_bounds__(256) void router_cvt(
    const float* __restrict__ x, const float* __restrict__ wr,
    float* __restrict__ scores, __bf16* __restrict__ xb)
{
    int wid  = (blockIdx.x * blockDim.x + threadIdx.x) >> 6;  // token id
    int lane = threadIdx.x & 63;
    const float* row = x + (size_t)wid * 1024;
    __bf16* orow = xb + (size_t)wid * 1024;
    double s = 0.0;
    #pragma unroll
    for (int it = 0; it < 2; ++it) {
        int base = it * 512 + lane * 8;
        float4 a  = *(const float4*)(row + base);
        float4 b  = *(const float4*)(row + base + 4);
        float4 wa = *(const float4*)(wr + base);
        float4 wc = *(const float4*)(wr + base + 4);
        s += (double)a.x * wa.x + (double)a.y * wa.y
           + (double)a.z * wa.z + (double)a.w * wa.w
           + (double)b.x * wc.x + (double)b.y * wc.y
           + (double)b.z * wc.z + (double)b.w * wc.w;
        bf16x8 v;
        v[0] = (__bf16)a.x; v[1] = (__bf16)a.y; v[2] = (__bf16)a.z; v[3] = (__bf16)a.w;
        v[4] = (__bf16)b.x; v[5] = (__bf16)b.y; v[6] = (__bf16)b.z; v[7] = (__bf16)b.w;
        *(bf16x8*)(orow + base) = v;
    }
    #pragma unroll
    for (int off = 32; off > 0; off >>= 1) s += __shfl_down(s, off, 64);
    if (lane == 0) scores[wid] = (float)s;
}

// ---------- weights -> bf16, three segments in one launch ----------
__global__ __launch_bounds__(256) void cvt3(
    const float* __restrict__ p0, const float* __restrict__ p1,
    const float* __restrict__ p2,
    __bf16* __restrict__ o0, __bf16* __restrict__ o1, __bf16* __restrict__ o2,
    int c0, int c1, int c2)
{
    int chunk = blockIdx.x * 256 + threadIdx.x;
    const float* in; __bf16* out;
    if (chunk < c0)                { in = p0 + (size_t)chunk * 8;             out = o0 + (size_t)chunk * 8; }
    else if (chunk < c0 + c1)      { int c = chunk - c0;      in = p1 + (size_t)c * 8; out = o1 + (size_t)c * 8; }
    else if (chunk < c0 + c1 + c2) { int c = chunk - c0 - c1; in = p2 + (size_t)c * 8; out = o2 + (size_t)c * 8; }
    else return;
    float4 a = *(const float4*)(in);
    float4 b = *(const float4*)(in + 4);
    bf16x8 v;
    v[0] = (__bf16)a.x; v[1] = (__bf16)a.y; v[2] = (__bf16)a.z; v[3] = (__bf16)a.w;
    v[4] = (__bf16)b.x; v[5] = (__bf16)b.y; v[6] = (__bf16)b.z; v[7] = (__bf16)b.w;
    *(bf16x8*)(out) = v;
}

// ---------------- per-batch top-k via 8-bit MSB-first radix select ----------------
// Same selected set as a full descending sort with tie-break "lower index wins".
__global__ __launch_bounds__(1024) void topk_build(
    const float* __restrict__ scores,
    int* __restrict__ sel_rows, int* __restrict__ byp_rows)
{
    const int L = 4096, K = 2048;
    __shared__ unsigned u[4096];
    __shared__ int hist[256];
    __shared__ int scan_s[1024];
    __shared__ unsigned s_pref;
    __shared__ int s_kk;
    int b = blockIdx.x, t = threadIdx.x;

    for (int i = t; i < L; i += 1024) {
        unsigned v = __float_as_uint(scores[b * L + i]);
        v = (v & 0x80000000u) ? ~v : (v | 0x80000000u);   // order-preserving map
        u[i] = v;
    }
    if (t == 0) { s_pref = 0; s_kk = K; }
    __syncthreads();

    // 4 passes, MSB first: find threshold value thr and count `need` of
    // elements equal to thr that are selected.
    for (int shift = 24; shift >= 0; shift -= 8) {
        if (t < 256) hist[t] = 0;
        __syncthreads();
        unsigned pref = s_pref;
        for (int i = t; i < L; i += 1024) {
            unsigned v = u[i];
            bool in_set = (shift == 24) || ((v >> (shift + 8)) == pref);
            if (in_set) atomicAdd(&hist[(v >> shift) & 255], 1);
        }
        __syncthreads();
        if (t == 0) {
            int kk = s_kk, cum = 0, bsel = 0;
            for (int j = 255; j >= 0; --j) {
                if (cum + hist[j] >= kk) { bsel = j; break; }
                cum += hist[j];
            }
            s_kk = kk - cum;                       // to take within bin bsel
            s_pref = (pref << 8) | (unsigned)bsel;
        }
        __syncthreads();
    }
    unsigned thr = s_pref;
    int need = s_kk;   // lowest-index `need` elements with u==thr are selected

    // rank among equals (stable by index), 4 consecutive elems per thread
    int base = t * 4;
    unsigned v0 = u[base], v1 = u[base+1], v2 = u[base+2], v3 = u[base+3];
    int eq0 = (v0 == thr), eq1 = (v1 == thr), eq2 = (v2 == thr), eq3 = (v3 == thr);
    scan_s[t] = eq0 + eq1 + eq2 + eq3;
    __syncthreads();
    for (int off = 1; off < 1024; off <<= 1) {
        int v = scan_s[t];
        if (t >= off) v += scan_s[t - off];
        __syncthreads();
        scan_s[t] = v;
        __syncthreads();
    }
    int erun = (t > 0) ? scan_s[t - 1] : 0;
    int sel[4];
    {
        int r = erun;
        sel[0] = (v0 > thr) || (eq0 && r < need); r += eq0;
        sel[1] = (v1 > thr) || (eq1 && r < need); r += eq1;
        sel[2] = (v2 > thr) || (eq2 && r < need); r += eq2;
        sel[3] = (v3 > thr) || (eq3 && r < need);
    }
    __syncthreads();

    // positions: prefix sum of selected flags
    scan_s[t] = sel[0] + sel[1] + sel[2] + sel[3];
    __syncthreads();
    for (int off = 1; off < 1024; off <<= 1) {
        int v = scan_s[t];
        if (t >= off) v += scan_s[t - off];
        __syncthreads();
        scan_s[t] = v;
        __syncthreads();
    }
    int run = (t > 0) ? scan_s[t - 1] : 0;
    #pragma unroll
    for (int j = 0; j < 4; ++j) {
        int idx = base + j;
        if (sel[j]) { sel_rows[b * K + run] = b * L + idx; run++; }
        else        { byp_rows[b * (L - K) + (idx - run)] = b * L + idx; }
    }
}

// XCD swizzle: with round-robin block->XCD (id%8), put all n-tiles of one
// m-tile on one XCD so the A-tile's reuse hits that XCD's L2.
__device__ __forceinline__ void xcd_map(int id, int nx, int& mt, int& nt) {
    int grp = nx * 8;
    mt = (id / grp) * 8 + (id & 7);
    nt = (id % grp) >> 3;
}

// ======== m97-style async GEMM, all-bf16 operands ========
template <bool GATHER_A, bool SCATTER_OUT, bool GELU_ACT, typename OT>
__global__ __launch_bounds__(256) void gemm_async(
    const __bf16* __restrict__ A, const __bf16* __restrict__ W,
    OT* __restrict__ Out, const int* __restrict__ rows,
    int K, int lda, int ldo)
{
    constexpr int BM = 128, BK = 64;
    __shared__ __align__(16) __bf16 As[BM * BK];
    __shared__ __align__(16) __bf16 Bs[BM * BK];
    __shared__ int rs[BM];

    const int tid = threadIdx.x;
    int mt, nt;
    xcd_map(blockIdx.y * gridDim.x + blockIdx.x, gridDim.x, mt, nt);
    const int m0 = mt * BM, n0 = nt * BM;
    if (tid < BM) rs[tid] = rows ? rows[m0 + tid] : (m0 + tid);
    __syncthreads();

    const int sub = tid >> 3;
    const int gc  = (tid & 7) ^ (sub & 7);
    const __bf16* aptr[4]; const __bf16* bptr[4];
    __bf16* adst[4]; __bf16* bdst[4];
    #pragma unroll
    for (int i = 0; i < 4; ++i) {
        int row = i * 32 + sub;
        int ar  = GATHER_A ? rs[row] : (m0 + row);
        aptr[i] = A + (size_t)ar * lda + gc * 8;
        bptr[i] = W + (size_t)(n0 + row) * K + gc * 8;
        adst[i] = As + (i * 256 + tid) * 8;
        bdst[i] = Bs + (i * 256 + tid) * 8;
    }

    f32x4 acc[4][4] = {};
    const int lane = tid & 63;
    const int wv = tid >> 6;
    const int wr = (wv >> 1) * 64, wc = (wv & 1) * 64;
    const int r = lane & 15, quad = lane >> 4;

    for (int k0 = 0; k0 < K; k0 += BK) {
        #pragma unroll
        for (int i = 0; i < 4; ++i) async_cp16(aptr[i] + k0, adst[i]);
        #pragma unroll
        for (int i = 0; i < 4; ++i) async_cp16(bptr[i] + k0, bdst[i]);
        __syncthreads();

        #pragma unroll
        for (int ks = 0; ks < 2; ++ks) {
            bf16x8 af[4], bfm[4];
            #pragma unroll
            for (int mi = 0; mi < 4; ++mi) {
                int row = wr + mi * 16 + r;
                int swz = (ks * 4 + quad) ^ (row & 7);
                af[mi] = *(const bf16x8*)(As + row * BK + swz * 8);
            }
            #pragma unroll
            for (int ni = 0; ni < 4; ++ni) {
                int row = wc + ni * 16 + r;
                int swz = (ks * 4 + quad) ^ (row & 7);
                bfm[ni] = *(const bf16x8*)(Bs + row * BK + swz * 8);
            }
            #pragma unroll
            for (int mi = 0; mi < 4; ++mi)
                #pragma unroll
                for (int ni = 0; ni < 4; ++ni)
                    acc[mi][ni] = __builtin_amdgcn_mfma_f32_16x16x32_bf16(
                        af[mi], bfm[ni], acc[mi][ni], 0, 0, 0);
        }
        __syncthreads();
    }

    #pragma unroll
    for (int mi = 0; mi < 4; ++mi) {
        #pragma unroll
        for (int reg = 0; reg < 4; ++reg) {
            int rowl = wr + mi * 16 + quad * 4 + reg;
            int orow = SCATTER_OUT ? rs[rowl] : (m0 + rowl);
            OT* op = Out + (size_t)orow * ldo + n0;
            #pragma unroll
            for (int ni = 0; ni < 4; ++ni) {
                float v = acc[mi][ni][reg];
                if (GELU_ACT) v = gelu_fast(v);
                op[wc + ni * 16 + r] = (OT)v;
            }
        }
    }
}

// ======== merged tail: z==0 -> FFN2 (h@w2^T, scatter sel),
//                       z==1 -> bypass (x@wb^T, gather+scatter byp) ========
__global__ __launch_bounds__(256) void gemm_tail(
    const __bf16* __restrict__ h, const __bf16* __restrict__ w2b,
    const __bf16* __restrict__ xb, const __bf16* __restrict__ wbb,
    float* __restrict__ Out,
    const int* __restrict__ sel_rows, const int* __restrict__ byp_rows)
{
    constexpr int BM = 128, BK = 64;
    __shared__ __align__(16) __bf16 As[BM * BK];
    __shared__ __align__(16) __bf16 Bs[BM * BK];
    __shared__ int rs[BM];

    const int z = blockIdx.z;
    const __bf16* A = z ? xb : h;
    const __bf16* W = z ? wbb : w2b;
    const int K = z ? 1024 : 4096;            // == lda for both
    const int* rows = z ? byp_rows : sel_rows;
    const bool gat = (z != 0);

    const int tid = threadIdx.x;
    int mt, nt;
    xcd_map(blockIdx.y * gridDim.x + blockIdx.x, gridDim.x, mt, nt);
    const int m0 = mt * BM, n0 = nt * BM;
    rs[tid & 127] = rows[m0 + (tid & 127)];
    __syncthreads();

    const int sub = tid >> 3;
    const int gc  = (tid & 7) ^ (sub & 7);
    const __bf16* aptr[4]; const __bf16* bptr[4];
    __bf16* adst[4]; __bf16* bdst[4];
    #pragma unroll
    for (int i = 0; i < 4; ++i) {
        int row = i * 32 + sub;
        int ar  = gat ? rs[row] : (m0 + row);
        aptr[i] = A + (size_t)ar * K + gc * 8;
        bptr[i] = W + (size_t)(n0 + row) * K + gc * 8;
        adst[i] = As + (i * 256 + tid) * 8;
        bdst[i] = Bs + (i * 256 + tid) * 8;
    }

    f32x4 acc[4][4] = {};
    const int lane = tid & 63;
    const int wv = tid >> 6;
    const int wrr = (wv >> 1) * 64, wc = (wv & 1) * 64;
    const int r = lane & 15, quad = lane >> 4;

    for (int k0 = 0; k0 < K; k0 += BK) {
        #pragma unroll
        for (int i = 0; i < 4; ++i) async_cp16(aptr[i] + k0, adst[i]);
        #pragma unroll
        for (int i = 0; i < 4; ++i) async_cp16(bptr[i] + k0, bdst[i]);
        __syncthreads();

        #pragma unroll
        for (int ks = 0; ks < 2; ++ks) {
            bf16x8 af[4], bfm[4];
            #pragma unroll
            for (int mi = 0; mi < 4; ++mi) {
                int row = wrr + mi * 16 + r;
                int swz = (ks * 4 + quad) ^ (row & 7);
                af[mi] = *(const bf16x8*)(As + row * BK + swz * 8);
            }
            #pragma unroll
            for (int ni = 0; ni < 4; ++ni) {
                int row = wc + ni * 16 + r;
                int swz = (ks * 4 + quad) ^ (row & 7);
                bfm[ni] = *(const bf16x8*)(Bs + row * BK + swz * 8);
            }
            #pragma unroll
            for (int mi = 0; mi < 4; ++mi)
                #pragma unroll
                for (int ni = 0; ni < 4; ++ni)
                    acc[mi][ni] = __builtin_amdgcn_mfma_f32_16x16x32_bf16(
                        af[mi], bfm[ni], acc[mi][ni], 0, 0, 0);
        }
        __syncthreads();
    }

    #pragma unroll
    for (int mi = 0; mi < 4; ++mi) {
        #pragma unroll
        for (int reg = 0; reg < 4; ++reg) {
            int rowl = wrr + mi * 16 + quad * 4 + reg;
            int orow = rs[rowl];
            float* op = Out + (size_t)orow * 1024 + n0;
            #pragma unroll
            for (int ni = 0; ni < 4; ++ni)
                op[wc + ni * 16 + r] = acc[mi][ni][reg];
        }
    }
}

extern "C" void kernel_launch(void* const* d_in, const int* in_sizes, int n_in,
                              void* d_out, int out_size, void* d_ws, size_t ws_size,
                              hipStream_t stream) {
    (void)in_sizes; (void)n_in; (void)out_size; (void)ws_size;
    const float* x  = (const float*)d_in[0];
    const float* wr = (const float*)d_in[1];
    const float* wb = (const float*)d_in[2];
    const float* w1 = (const float*)d_in[3];
    const float* w2 = (const float*)d_in[4];
    float* out = (float*)d_out;

    const int B = 4, L = 4096, D = 1024, DFF = 4096, KSEL = 2048;
    const int M = B * KSEL;           // 8192
    const int NTOK = B * L;           // 16384

    size_t n_x = (size_t)NTOK * D, n_wb = (size_t)D * D;
    size_t n_w1 = (size_t)DFF * D, n_w2 = (size_t)D * DFF;

    char* ws = (char*)d_ws;
    float* scores = (float*)ws;            ws += sizeof(float) * (size_t)NTOK;
    int* sel_rows = (int*)ws;              ws += sizeof(int) * (size_t)M;
    int* byp_rows = (int*)ws;              ws += sizeof(int) * (size_t)M;
    uintptr_t up = ((uintptr_t)ws + 255) & ~(uintptr_t)255;
    __bf16* xb  = (__bf16*)up;             up += 2 * n_x;
    __bf16* wbb = (__bf16*)up;             up += 2 * n_wb;
    __bf16* w1b = (__bf16*)up;             up += 2 * n_w1;
    __bf16* w2b = (__bf16*)up;             up += 2 * n_w2;
    up = (up + 255) & ~(uintptr_t)255;
    __bf16* h   = (__bf16*)up;             // 8192 x 4096 bf16 = 64 MiB

    router_cvt<<<NTOK / 4, 256, 0, stream>>>(x, wr, scores, xb);
    cvt3<<<(int)((n_wb + n_w1 + n_w2) / 8 / 256), 256, 0, stream>>>(
        wb, w1, w2, wbb, w1b, w2b,
        (int)(n_wb / 8), (int)(n_w1 / 8), (int)(n_w2 / 8));
    topk_build<<<B, 1024, 0, stream>>>(scores, sel_rows, byp_rows);

    // h = gelu(x[sel] @ w1^T)     (M=8192, N=DFF, K=D), 2048 blocks
    gemm_async<true, false, true, __bf16>
        <<<dim3(DFF / 128, M / 128), 256, 0, stream>>>(
        xb, w1b, h, sel_rows, D, D, DFF);
    // merged: out[sel] = h @ w2^T  and  out[byp] = x[byp] @ wb^T, 1024 blocks
    gemm_tail<<<dim3(D / 128, M / 128, 2), 256, 0, stream>>>(
        h, w2b, xb, wbb, out, sel_rows, byp_rows);
}